// Round 10
// baseline (363.065 us; speedup 1.0000x reference)
//
#include <hip/hip_runtime.h>

// RGAT 2-layer + BN/ELU + head for MI355X (gfx950).
// Float inputs may be bf16 OR fp32 (runtime-detected); ints are int32.
// Internal compute fp32; xt message tables stored bf16 (slot15 = f16 dk).
//
// Round-17: build-chain slimming (round-9 meas: 309.6 µs; REC 4096 tweak
// confirmed build is latency-sensitive, -8.3 µs).
//  (a) k_bucket emits global deg[dst] atomics in pass 1 (L2-resident, 200 KB,
//      ~32 hits/ctr — round-15 showed hist atomics were NOT the bottleneck,
//      only scatter STORES were). k_b2csr drops its histogram pass over tmp
//      (one fewer 12.8 MB read + 14 fewer barriers): reads deg, scans 128,
//      single scatter pass.
//  (b) k_bucket redistribution: bucket id rides in y's high 16 bits (eattr
//      bf16-compressed at staging — same value b2csr produced later), killing
//      the 9-step LDS binary search per record.
// Round-16: bucketed CSR build (round-15 flat scatter FAILED: random 8B
// stores write-allocated 64B lines -> 101.8 MB WRITE_SIZE, 115 µs).
// tmp record: x = src | et<<23 | ldst<<25 ; y = bkt<<16 | bf16(eattr).
// ebuf record: x = src | et<<20 ; y = dst<<16 | bf16(eattr).
// Layer-1 transform: MFMA GEMM [N,128]@[128,80] (xt cols + dk-in-col15 + dq).
// Round-14: alpha fused INTO gather (dk in xt slot 15 f16; dq wave-uniform;
// exp(leakyrelu) inline). Round-13: 4-way unrolled gather for MLP.
// Round-12 lesson: Σe must reach every lane. BN stats separate (round-8
// atomic lesson). k_prep parallel (round-10 lesson).

typedef unsigned short ushort_t;
typedef unsigned int uint_t;
typedef __attribute__((ext_vector_type(8))) short bf16x8;   // 8 bf16 = 4 VGPRs
typedef __attribute__((ext_vector_type(4))) float f32x4;

#define NEG_SLOPE 0.2f
#define BN_EPS 1e-5f
#define NBUCK 512   // partition buckets
#define REC 4096    // staged records per k_bucket block (32 KB LDS)

__device__ __forceinline__ float bf2f(ushort_t u) {
    return __uint_as_float(((uint_t)u) << 16);
}
__device__ __forceinline__ ushort_t f2bf(float f) {
    uint_t x = __float_as_uint(f);
    x += 0x7FFFu + ((x >> 16) & 1u);   // round-to-nearest-even
    return (ushort_t)(x >> 16);
}
__device__ __forceinline__ float h2f(ushort_t u) {
    _Float16 h = __builtin_bit_cast(_Float16, u);
    return (float)h;
}
__device__ __forceinline__ ushort_t f2h(float f) {
    _Float16 h = (_Float16)f;
    return __builtin_bit_cast(ushort_t, h);
}
// generic float load: bf16 (isb=1) or fp32 (isb=0)
__device__ __forceinline__ float loadf(const void* p, int i, int isb) {
    return isb ? bf2f(((const ushort_t*)p)[i]) : ((const float*)p)[i];
}
// select dq[et] from 4 wave-resident regs
__device__ __forceinline__ float sel4(float a0, float a1, float a2, float a3, int et) {
    float lo = (et == 1) ? a1 : a0;
    float hi = (et == 3) ? a3 : a2;
    return (et >= 2) ? hi : lo;
}

// ---------------- prep: dtype detect + init cursors/deg/stats + weight prep ----------------
__global__ __launch_bounds__(256) void k_prep(const uint_t* __restrict__ x,
                                              const void* __restrict__ W1,
                                              const void* __restrict__ W2,
                                              const void* __restrict__ q1b,
                                              const void* __restrict__ k1b,
                                              const void* __restrict__ We1,
                                              const void* __restrict__ e1v,
                                              const void* __restrict__ We2,
                                              const void* __restrict__ e2v,
                                              int* __restrict__ dflag,
                                              int* __restrict__ bcur,
                                              int* __restrict__ deg,
                                              float* __restrict__ stats1,
                                              float* __restrict__ stats2,
                                              float* __restrict__ cbuf,
                                              ushort_t* __restrict__ Wsw,
                                              float* __restrict__ Wf2, int cap, int N) {
    __shared__ int cnt;
    int t = threadIdx.x;
    if (t == 0) cnt = 0;
    __syncthreads();
    uint_t u = x[t * 37];
    uint_t lo_exp = (u >> 7) & 0xFF;
    atomicAdd(&cnt, (lo_exp >= 96 && lo_exp <= 150) ? 1 : 0);
    __syncthreads();
    int isb = (cnt > 192) ? 1 : 0;
    // zero the degree array (grid-stride, all blocks)
    for (int i = blockIdx.x * 256 + t; i < N; i += gridDim.x * 256) deg[i] = 0;
    if (blockIdx.x == 0) {
        if (t == 0) {
            dflag[0] = isb;
            float c1 = 0.f;
            for (int o = 0; o < 15; ++o) c1 += loadf(We1, o, isb) * loadf(e1v, o, isb);
            float c2 = 0.f;
            for (int o = 0; o < 10; ++o) c2 += loadf(We2, o, isb) * loadf(e2v, o, isb);
            cbuf[0] = c1;
            cbuf[1] = c2;
        }
        for (int i = t; i < NBUCK; i += 256) bcur[i] = i * cap;
        stats1[t] = 0.f;
        stats2[t] = 0.f;
        for (int idx = t; idx < 15 * 40; idx += 256) {
            int f = idx / 40, j = idx % 40, r = j / 10, o = j % 10;
            Wf2[idx] = loadf(W2, (r * 15 + f) * 10 + o, isb);
        }
    }
    // grid-stride over the 20*64*8 = 10240 Wsw elements
    for (int idx = blockIdx.x * 256 + t; idx < 20 * 64 * 8; idx += gridDim.x * 256) {
        int j = idx & 7, lane = (idx >> 3) & 63, fr = idx >> 9;
        int ks = fr / 5, ct = fr % 5;
        int k = ks * 32 + (lane >> 4) * 8 + j;   // feature row in [0,128)
        int c = ct * 16 + (lane & 15);           // packed col in [0,80)
        float v = 0.f;
        if (c < 64) {
            int r = c >> 4, o = c & 15;
            if (o < 15) {
                v = loadf(W1, (r * 128 + k) * 15 + o, isb);
            } else {   // col 15 of each relation block: k-projection (dk)
                float s = 0.f;
#pragma unroll
                for (int oo = 0; oo < 15; ++oo)
                    s += loadf(W1, (r * 128 + k) * 15 + oo, isb) * loadf(k1b, oo, isb);
                v = s;
            }
        } else if (c < 68) {   // q-projection (dq) for relation c-64
            int r = c - 64;
            float s = 0.f;
#pragma unroll
            for (int oo = 0; oo < 15; ++oo)
                s += loadf(W1, (r * 128 + k) * 15 + oo, isb) * loadf(q1b, oo, isb);
            v = s;
        }
        Wsw[idx] = f2bf(v);
    }
}

// ---------------- LDS-staged bucket partition (fixed-capacity buckets) ----------------
// tmp record: x = src | et<<23 | ldst<<25 ; y = bkt<<16 | bf16(eattr)
__global__ __launch_bounds__(512) void k_bucket(const int* __restrict__ ei,
                                                const int* __restrict__ et,
                                                const void* __restrict__ ea,
                                                const int* __restrict__ flag,
                                                int* __restrict__ bcur,
                                                int* __restrict__ deg,
                                                int2* __restrict__ tmp,
                                                int E, int npb) {
    extern __shared__ int2 srec[];           // REC records = 32 KB
    __shared__ int cnt[NBUCK];
    __shared__ int lofs[NBUCK + 1];
    __shared__ int gpos[NBUCK];
    int t = threadIdx.x;
    int isb = flag[0];
    cnt[t] = 0;
    __syncthreads();
    int e0 = blockIdx.x * REC;
    for (int i = 0; i < REC / 512; ++i) {
        int e = e0 + i * 512 + t;
        if (e < E) {
            int d = ei[E + e];
            atomicAdd(&deg[d], 1);              // global degree (for b2csr scan)
            atomicAdd(&cnt[d / npb], 1);
        }
    }
    __syncthreads();
    int myc = cnt[t];
    for (int off = 1; off < NBUCK; off <<= 1) {
        int v = (t >= off) ? cnt[t - off] : 0;
        __syncthreads();
        cnt[t] += v;
        __syncthreads();
    }
    lofs[t] = cnt[t] - myc;
    if (t == NBUCK - 1) lofs[NBUCK] = cnt[NBUCK - 1];
    __syncthreads();
    cnt[t] = lofs[t];   // reuse as local cursor
    __syncthreads();
    for (int i = 0; i < REC / 512; ++i) {
        int e = e0 + i * 512 + t;
        if (e < E) {
            int d = ei[E + e];
            int b = d / npb;
            int ldst = d - b * npb;
            int idx = atomicAdd(&cnt[b], 1);
            int2 r;
            r.x = (int)((uint_t)ei[e] | ((uint_t)et[e] << 23) | ((uint_t)ldst << 25));
            r.y = (int)(((uint_t)b << 16) | (uint_t)f2bf(loadf(ea, e, isb)));
            srec[idx] = r;
        }
    }
    __syncthreads();
    int c_b = lofs[t + 1] - lofs[t];
    gpos[t] = atomicAdd(&bcur[t], c_b);
    __syncthreads();
    int total = lofs[NBUCK];
    for (int i = t; i < total; i += 512) {
        int2 rr = srec[i];
        int bkt = (int)(((uint_t)rr.y) >> 16);   // bucket id from record (no binary search)
        tmp[gpos[bkt] + (i - lofs[bkt])] = rr;
    }
}

// ---------------- per-bucket finalize: single pass via deg scan -> ebuf + rs/re ----------------
// ebuf record: x = src | et<<20 ; y = dst<<16 | bf16(eattr)
__global__ __launch_bounds__(256) void k_b2csr(const int2* __restrict__ tmp,
                                               const int* __restrict__ bcur,
                                               const int* __restrict__ deg,
                                               int* __restrict__ rs,
                                               int* __restrict__ re,
                                               int2* __restrict__ ebuf,
                                               int N, int npb, int cap) {
    __shared__ int cnt[128];
    __shared__ int lofs[129];
    int b = blockIdx.x, t = threadIdx.x;
    int s0 = b * cap;
    int s1 = bcur[b];                 // base + count (post-partition)
    int node0 = b * npb;
    int d = 0;
    if (t < 128) {
        d = (t < npb && node0 + t < N) ? deg[node0 + t] : 0;
        cnt[t] = d;
    }
    __syncthreads();
    for (int off = 1; off < 128; off <<= 1) {
        int v = (t >= off && t < 128) ? cnt[t - off] : 0;
        __syncthreads();
        if (t < 128) cnt[t] += v;
        __syncthreads();
    }
    if (t < 128) {
        lofs[t] = cnt[t] - d;
        if (t == 127) lofs[128] = cnt[127];
    }
    __syncthreads();
    if (t < npb && node0 + t < N) {
        rs[node0 + t] = s0 + lofs[t];
        re[node0 + t] = s0 + lofs[t + 1];
    }
    if (t < 128) cnt[t] = lofs[t];   // reuse as cursor
    __syncthreads();
    for (int p = s0 + t; p < s1; p += 256) {
        int2 r = tmp[p];
        uint_t x = (uint_t)r.x;
        int ldst = (x >> 25) & 0x7F;
        int idx = atomicAdd(&cnt[ldst], 1);
        int2 o;
        o.x = (int)(x & 0x7FFFFF) | (((int)(x >> 23) & 3) << 20);  // src | et<<20
        o.y = (int)(((uint_t)(node0 + ldst) << 16) |
                    ((uint_t)r.y & 0xFFFFu));                      // dst | bf16(ea)
        ebuf[s0 + idx] = o;
    }
}

// ---------------- layer-1 transform: MFMA GEMM, bf16 xt out (slot15 = f16 dk) ----------------
__global__ __launch_bounds__(256) void k_t1(const void* __restrict__ xin,
                                            const ushort_t* __restrict__ Wsw,
                                            const int* __restrict__ flag,
                                            ushort_t* __restrict__ xt,
                                            float* __restrict__ dq,
                                            int N, int ntiles, int nwaves) {
    int isb = flag[0];
    int lane = threadIdx.x & 63;
    int gw = blockIdx.x * 4 + (threadIdx.x >> 6);
    bf16x8 bfr[20];
    const uint4* wq = (const uint4*)Wsw;
#pragma unroll
    for (int fr = 0; fr < 20; ++fr)
        bfr[fr] = __builtin_bit_cast(bf16x8, wq[fr * 64 + lane]);
    int row = lane & 15, quad = lane >> 4;
    for (int tile = gw; tile < ntiles; tile += nwaves) {
        int n0 = tile * 16;
        f32x4 acc[5];
#pragma unroll
        for (int ct = 0; ct < 5; ++ct) acc[ct] = (f32x4){0.f, 0.f, 0.f, 0.f};
        int nA = n0 + row;
        if (nA >= N) nA = N - 1;
#pragma unroll
        for (int ks = 0; ks < 4; ++ks) {
            bf16x8 af;
            if (isb) {
                uint4 u = *(const uint4*)((const ushort_t*)xin + (size_t)nA * 128 + ks * 32 + quad * 8);
                af = __builtin_bit_cast(bf16x8, u);
            } else {
                const float* xf = (const float*)xin + (size_t)nA * 128 + ks * 32 + quad * 8;
#pragma unroll
                for (int j = 0; j < 8; ++j) af[j] = (short)f2bf(xf[j]);
            }
#pragma unroll
            for (int ct = 0; ct < 5; ++ct)
                acc[ct] = __builtin_amdgcn_mfma_f32_16x16x32_bf16(af, bfr[ks * 5 + ct], acc[ct], 0, 0, 0);
        }
#pragma unroll
        for (int i = 0; i < 4; ++i) {
            int n = n0 + quad * 4 + i;
            if (n < N) {
#pragma unroll
                for (int ct = 0; ct < 4; ++ct) {
                    float val = acc[ct][i];
                    // row 15 holds dk (k-projection packed as GEMM col 15) -> f16
                    ushort_t bits = (row == 15) ? f2h(val) : f2bf(val);
                    xt[(size_t)n * 64 + ct * 16 + row] = bits;
                }
                if (row < 4) dq[n * 4 + row] = acc[4][i];
            }
        }
    }
}

// ---------------- layer-2 transform: BN1+ELU fused, wave-per-relation, bf16 xt ----------------
__global__ __launch_bounds__(256) void k_t2(const float* __restrict__ in,
                                            const float* __restrict__ stats,
                                            const void* __restrict__ g,
                                            const void* __restrict__ beta,
                                            const float* __restrict__ Wf,
                                            const void* __restrict__ qb,
                                            const void* __restrict__ kb,
                                            const int* __restrict__ flag,
                                            ushort_t* __restrict__ xt,
                                            float* __restrict__ dq, int N) {
    int isb = flag[0];
    int t = threadIdx.x;
    int lane = t & 63;
    int r = t >> 6;                 // wave-uniform relation
    int n = blockIdx.x * 64 + lane;
    if (n >= N) return;
    float invN = 1.f / (float)N;
    float v[15];
#pragma unroll
    for (int c = 0; c < 15; ++c) {
        float mean = stats[c * 16] * invN;
        float var = stats[c * 16 + 8] * invN - mean * mean;
        float inv = rsqrtf(var + BN_EPS);
        float h = (in[(size_t)n * 15 + c] - mean) * inv * loadf(g, c, isb) + loadf(beta, c, isb);
        v[c] = h > 0.f ? h : expm1f(h);  // ELU
    }
    float acc[10];
#pragma unroll
    for (int o = 0; o < 10; ++o) acc[o] = 0.f;
#pragma unroll
    for (int f = 0; f < 15; ++f) {
        const float* wp = Wf + f * 40 + r * 10;
#pragma unroll
        for (int o = 0; o < 10; ++o) acc[o] += v[f] * wp[o];
    }
    float sq = 0.f, sk = 0.f;
#pragma unroll
    for (int o = 0; o < 10; ++o) {
        sq += acc[o] * loadf(qb, o, isb);
        sk += acc[o] * loadf(kb, o, isb);
    }
    dq[n * 4 + r] = sq;
    ushort_t* xr = xt + (size_t)n * 64 + r * 16;
    uint_t pk[8];
#pragma unroll
    for (int j = 0; j < 5; ++j)
        pk[j] = (uint_t)f2bf(acc[2 * j]) | ((uint_t)f2bf(acc[2 * j + 1]) << 16);
    pk[5] = 0; pk[6] = 0;
    pk[7] = ((uint_t)f2h(sk)) << 16;   // slot 15 = dk (f16), slot 14 = 0
    *(uint4*)(xr)     = make_uint4(pk[0], pk[1], pk[2], pk[3]);
    *(uint4*)(xr + 8) = make_uint4(pk[4], pk[5], pk[6], pk[7]);
}

// ---------------- per-node gather with FUSED alpha: single pass, 4-way unrolled ----------------
// 4 edge-groups x 16 channel-lanes. Per edge: 32B xt line already carries dk
// in slot 15 (lane ch==15); dq[n*4+et] is wave-uniform (4 regs, cndmask
// select); alpha = dq + dk + c*ea, e = exp(leakyrelu(alpha)) computed by all
// 16 lanes of the group (1 wave-slot/edge). s accumulated in every lane and
// reduced with the same xor(16)+xor(32) pattern as acc (round-12 lesson).
template <int O>
__global__ __launch_bounds__(256) void k_gather(const int* __restrict__ rs,
                                                const int* __restrict__ re,
                                                const int2* __restrict__ ebuf,
                                                const ushort_t* __restrict__ xt,
                                                const float* __restrict__ dq,
                                                const float* __restrict__ cp,
                                                const void* __restrict__ bb,
                                                const int* __restrict__ flag,
                                                float* __restrict__ out, int N) {
    int isb = flag[0];
    int lane = threadIdx.x & 63;
    int w = threadIdx.x >> 6;
    int n = blockIdx.x * 4 + w;
    if (n >= N) return;
    int start = rs[n], end = re[n];
    int ch = lane & 15;
    int gb = lane & 48;               // group base lane (g*16)
    bool hi15 = (ch == 15);
    float c = cp[0];
    float q0 = dq[n * 4], q1 = dq[n * 4 + 1], q2 = dq[n * 4 + 2], q3 = dq[n * 4 + 3];
    float acc = 0.f, s = 0.f;
    int p = start + (gb >> 4);
    // 4-way unrolled body: advances 16 edges (4 per group) per step
    for (; p + 12 < end; p += 16) {
        int2 v0 = ebuf[p];
        int2 v1 = ebuf[p + 4];
        int2 v2 = ebuf[p + 8];
        int2 v3 = ebuf[p + 12];
        ushort_t u0 = xt[(size_t)((v0.x & 0xFFFFF) * 4 + (v0.x >> 20)) * 16 + ch];
        ushort_t u1 = xt[(size_t)((v1.x & 0xFFFFF) * 4 + (v1.x >> 20)) * 16 + ch];
        ushort_t u2 = xt[(size_t)((v2.x & 0xFFFFF) * 4 + (v2.x >> 20)) * 16 + ch];
        ushort_t u3 = xt[(size_t)((v3.x & 0xFFFFF) * 4 + (v3.x >> 20)) * 16 + ch];
        float x0 = hi15 ? h2f(u0) : bf2f(u0);
        float x1 = hi15 ? h2f(u1) : bf2f(u1);
        float x2 = hi15 ? h2f(u2) : bf2f(u2);
        float x3 = hi15 ? h2f(u3) : bf2f(u3);
        float dk0 = __shfl(x0, gb + 15, 64);
        float dk1 = __shfl(x1, gb + 15, 64);
        float dk2 = __shfl(x2, gb + 15, 64);
        float dk3 = __shfl(x3, gb + 15, 64);
        float a0 = sel4(q0, q1, q2, q3, v0.x >> 20) + dk0 + c * bf2f((ushort_t)(v0.y & 0xFFFFu));
        float a1 = sel4(q0, q1, q2, q3, v1.x >> 20) + dk1 + c * bf2f((ushort_t)(v1.y & 0xFFFFu));
        float a2 = sel4(q0, q1, q2, q3, v2.x >> 20) + dk2 + c * bf2f((ushort_t)(v2.y & 0xFFFFu));
        float a3 = sel4(q0, q1, q2, q3, v3.x >> 20) + dk3 + c * bf2f((ushort_t)(v3.y & 0xFFFFu));
        float e0 = __expf(fmaxf(a0, NEG_SLOPE * a0));
        float e1 = __expf(fmaxf(a1, NEG_SLOPE * a1));
        float e2 = __expf(fmaxf(a2, NEG_SLOPE * a2));
        float e3 = __expf(fmaxf(a3, NEG_SLOPE * a3));
        s += (e0 + e1) + (e2 + e3);
        acc += e0 * x0;
        acc += e1 * x1;
        acc += e2 * x2;
        acc += e3 * x3;
    }
    for (; p < end; p += 4) {
        int2 v = ebuf[p];
        ushort_t u = xt[(size_t)((v.x & 0xFFFFF) * 4 + (v.x >> 20)) * 16 + ch];
        float x = hi15 ? h2f(u) : bf2f(u);
        float dk = __shfl(x, gb + 15, 64);
        float a = sel4(q0, q1, q2, q3, v.x >> 20) + dk + c * bf2f((ushort_t)(v.y & 0xFFFFu));
        float e = __expf(fmaxf(a, NEG_SLOPE * a));
        acc += e * x;
        s += e;
    }
    s   += __shfl_xor(s, 16, 64);
    s   += __shfl_xor(s, 32, 64);
    acc += __shfl_xor(acc, 16, 64);
    acc += __shfl_xor(acc, 32, 64);
    if (lane < O) out[(size_t)n * O + lane] = acc / (s + 1e-16f) + loadf(bb, lane, isb);
}

// ---------------- BN batch statistics (separate, low-block-count) ----------------
// stats layout: channel c -> S[c*16] = sum, S[c*16+8] = sumsq (64B stride)
template <int C>
__global__ __launch_bounds__(256) void k_bnstats(const float* __restrict__ in,
                                                 float* __restrict__ S, int N) {
    int t = threadIdx.x;
    int ch = t & 15, rg = t >> 4;
    float s1 = 0.f, s2 = 0.f;
    int row0 = blockIdx.x * 256;
    int rowEnd = row0 + 256;
    if (rowEnd > N) rowEnd = N;
    if (ch < C) {
        for (int r = row0 + rg; r < rowEnd; r += 16) {
            float v = in[(size_t)r * C + ch];
            s1 += v;
            s2 += v * v;
        }
    }
    __shared__ float L1[256], L2[256];
    L1[t] = s1; L2[t] = s2;
    __syncthreads();
    for (int k = 128; k >= 16; k >>= 1) {
        if (t < k) { L1[t] += L1[t + k]; L2[t] += L2[t + k]; }
        __syncthreads();
    }
    if (t < C) {
        atomicAdd(&S[t * 16], L1[t]);
        atomicAdd(&S[t * 16 + 8], L2[t]);
    }
}

// ---------------- BN2 + ELU + head, bf16-or-fp32 output ----------------
__global__ __launch_bounds__(256) void k_head(const float* __restrict__ in,
                                              const float* __restrict__ stats,
                                              const void* __restrict__ g,
                                              const void* __restrict__ beta,
                                              const void* __restrict__ wh,
                                              const void* __restrict__ bh,
                                              const int* __restrict__ flag,
                                              void* __restrict__ out, int N) {
    int isb = flag[0];
    int n = blockIdx.x * 256 + threadIdx.x;
    if (n >= N) return;
    float invN = 1.f / (float)N;
    float r = loadf(bh, 0, isb);
#pragma unroll
    for (int c = 0; c < 10; ++c) {
        float mean = stats[c * 16] * invN;
        float var = stats[c * 16 + 8] * invN - mean * mean;
        float inv = rsqrtf(var + BN_EPS);
        float h = (in[(size_t)n * 10 + c] - mean) * inv * loadf(g, c, isb) + loadf(beta, c, isb);
        float e = h > 0.f ? h : expm1f(h);
        r += e * loadf(wh, c, isb);
    }
    if (isb) ((ushort_t*)out)[n] = f2bf(r);
    else     ((float*)out)[n] = r;
}

extern "C" void kernel_launch(void* const* d_in, const int* in_sizes, int n_in,
                              void* d_out, int out_size, void* d_ws, size_t ws_size,
                              hipStream_t stream) {
    const void* node_emb  = d_in[0];
    const int*  edge_index = (const int*)d_in[1];
    const int*  edge_types = (const int*)d_in[2];
    const void* edge_attr = d_in[3];
    const void* W1  = d_in[4];
    const void* q1  = d_in[5];
    const void* k1  = d_in[6];
    const void* e1  = d_in[7];
    const void* We1 = d_in[8];
    const void* b1  = d_in[9];
    const void* W2  = d_in[10];
    const void* q2  = d_in[11];
    const void* k2  = d_in[12];
    const void* e2  = d_in[13];
    const void* We2 = d_in[14];
    const void* b2  = d_in[15];
    const void* g1  = d_in[16];
    const void* beta1 = d_in[17];
    const void* g2  = d_in[18];
    const void* beta2 = d_in[19];
    const void* w_head = d_in[20];
    const void* b_head = d_in[21];

    int N = in_sizes[0] / 128;
    int E = in_sizes[1] / 2;
    int npb = (N + NBUCK - 1) / NBUCK;         // nodes per bucket (98)
    int nbuck = (N + npb - 1) / npb;           // used buckets (511)
    int cap = E / nbuck + 512;                 // ~9 sigma slack for random dst
    size_t slots = (size_t)nbuck * cap;        // padded edge-slot count

    char* ws = (char*)d_ws;
    size_t off = 0;
    auto alloc = [&](size_t bytes) -> void* {
        void* p = ws + off;
        off = (off + bytes + 255) & ~(size_t)255;
        return p;
    };
    int*   rs      = (int*)alloc((size_t)N * 4);
    int*   re      = (int*)alloc((size_t)N * 4);
    int*   bcur    = (int*)alloc((NBUCK) * 4);
    int*   deg     = (int*)alloc((size_t)N * 4);
    int*   dflag   = (int*)alloc(256);
    float* cbuf    = (float*)alloc(256);
    int2*  ebuf    = (int2*)alloc(slots * 8);
    // xt (bf16, 32B per (node,rel) row) overlays etmp: tmp dead before k_t1
    size_t big = (size_t)N * 64 * 2;
    if (slots * 8 > big) big = slots * 8;
    ushort_t* xt1  = (ushort_t*)alloc(big);
    int2*  etmp    = (int2*)xt1;
    float* dq1     = (float*)alloc((size_t)N * 16);
    float* out1    = (float*)alloc((size_t)N * 15 * 4);   // out2 overlays
    float* stats1  = (float*)alloc(256 * 4);   // 16 floats (64B) per channel
    float* stats2  = (float*)alloc(256 * 4);
    ushort_t* Wsw  = (ushort_t*)alloc(20 * 64 * 8 * 2);   // 20 KB B-frags
    float* Wf2     = (float*)alloc(600 * 4);
    // overlays (lifetimes disjoint):
    ushort_t* xt2 = xt1;
    float* dq2  = dq1;
    float* out2 = out1;

    int NB_N = (N + 255) / 256;
    int NB_T2 = (N + 63) / 64;
    int NB_G = (N + 3) / 4;
    int NB_B = (E + REC - 1) / REC;      // 391 blocks, 32 KB LDS, 4 blocks/CU
    int ntiles = (N + 15) / 16;
    int NB_T1 = 391;
    int nwaves = NB_T1 * 4;

    k_prep<<<40, 256, 0, stream>>>((const uint_t*)node_emb, W1, W2, q1, k1,
                                   We1, e1, We2, e2,
                                   dflag, bcur, deg, stats1, stats2, cbuf, Wsw, Wf2, cap, N);
    k_bucket<<<NB_B, 512, REC * sizeof(int2), stream>>>(edge_index, edge_types, edge_attr,
                                                        dflag, bcur, deg, etmp, E, npb);
    k_b2csr<<<nbuck, 256, 0, stream>>>(etmp, bcur, deg, rs, re, ebuf, N, npb, cap);

    k_t1<<<NB_T1, 256, 0, stream>>>(node_emb, Wsw, dflag, xt1, dq1, N, ntiles, nwaves);
    k_gather<15><<<NB_G, 256, 0, stream>>>(rs, re, ebuf, xt1, dq1, cbuf, b1, dflag, out1, N);
    k_bnstats<15><<<NB_N, 256, 0, stream>>>(out1, stats1, N);
    k_t2<<<NB_T2, 256, 0, stream>>>(out1, stats1, g1, beta1, Wf2, q2, k2, dflag, xt2, dq2, N);
    k_gather<10><<<NB_G, 256, 0, stream>>>(rs, re, ebuf, xt2, dq2, cbuf + 1, b2, dflag, out2, N);
    k_bnstats<10><<<NB_N, 256, 0, stream>>>(out2, stats2, N);
    k_head<<<NB_N, 256, 0, stream>>>(out2, stats2, g2, beta2, w_head, b_head, dflag, d_out, N);
}

// Round 11
// 300.532 us; speedup vs baseline: 1.2081x; 1.2081x over previous
//
#include <hip/hip_runtime.h>

// RGAT 2-layer + BN/ELU + head for MI355X (gfx950).
// Float inputs may be bf16 OR fp32 (runtime-detected); ints are int32.
// Internal compute fp32; xt message tables stored bf16 (slot15 = f16 dk).
//
// Round-18: REVERT round-17 edit (a) — global deg[dst] atomics in k_bucket
// caused 66.7 MB WRITE_SIZE / 88 µs (random-address RMW = write-allocate
// amplification, same failure mode as round-15's flat scatter; rule: only
// CONTIGUOUS global writes at E-scale). k_b2csr histogram pass over tmp
// restored (contiguous reads were never the cost). Edit (b) KEPT: bucket id
// rides in tmp y's high 16 bits (eattr bf16-compressed at staging), so
// k_bucket redistribution needs no 9-step LDS binary search.
// Round-16: bucketed CSR build, REC=4096 (32 KB LDS, 4 blocks/CU).
// tmp record: x = src | et<<23 | ldst<<25 ; y = bkt<<16 | bf16(eattr).
// ebuf record: x = src | et<<20 ; y = dst<<16 | bf16(eattr).
// Layer-1 transform: MFMA GEMM [N,128]@[128,80] (xt cols + dk-in-col15 + dq).
// Round-14: alpha fused INTO gather (dk in xt slot 15 f16; dq wave-uniform;
// exp(leakyrelu) inline). Round-13: 4-way unrolled gather for MLP.
// Round-12 lesson: Σe must reach every lane. BN stats separate (round-8
// atomic lesson). k_prep parallel (round-10 lesson).

typedef unsigned short ushort_t;
typedef unsigned int uint_t;
typedef __attribute__((ext_vector_type(8))) short bf16x8;   // 8 bf16 = 4 VGPRs
typedef __attribute__((ext_vector_type(4))) float f32x4;

#define NEG_SLOPE 0.2f
#define BN_EPS 1e-5f
#define NBUCK 512   // partition buckets
#define REC 4096    // staged records per k_bucket block (32 KB LDS)

__device__ __forceinline__ float bf2f(ushort_t u) {
    return __uint_as_float(((uint_t)u) << 16);
}
__device__ __forceinline__ ushort_t f2bf(float f) {
    uint_t x = __float_as_uint(f);
    x += 0x7FFFu + ((x >> 16) & 1u);   // round-to-nearest-even
    return (ushort_t)(x >> 16);
}
__device__ __forceinline__ float h2f(ushort_t u) {
    _Float16 h = __builtin_bit_cast(_Float16, u);
    return (float)h;
}
__device__ __forceinline__ ushort_t f2h(float f) {
    _Float16 h = (_Float16)f;
    return __builtin_bit_cast(ushort_t, h);
}
// generic float load: bf16 (isb=1) or fp32 (isb=0)
__device__ __forceinline__ float loadf(const void* p, int i, int isb) {
    return isb ? bf2f(((const ushort_t*)p)[i]) : ((const float*)p)[i];
}
// select dq[et] from 4 wave-resident regs
__device__ __forceinline__ float sel4(float a0, float a1, float a2, float a3, int et) {
    float lo = (et == 1) ? a1 : a0;
    float hi = (et == 3) ? a3 : a2;
    return (et >= 2) ? hi : lo;
}

// ---------------- prep: dtype detect + init cursors/stats + weight prep ----------------
__global__ __launch_bounds__(256) void k_prep(const uint_t* __restrict__ x,
                                              const void* __restrict__ W1,
                                              const void* __restrict__ W2,
                                              const void* __restrict__ q1b,
                                              const void* __restrict__ k1b,
                                              const void* __restrict__ We1,
                                              const void* __restrict__ e1v,
                                              const void* __restrict__ We2,
                                              const void* __restrict__ e2v,
                                              int* __restrict__ dflag,
                                              int* __restrict__ bcur,
                                              float* __restrict__ stats1,
                                              float* __restrict__ stats2,
                                              float* __restrict__ cbuf,
                                              ushort_t* __restrict__ Wsw,
                                              float* __restrict__ Wf2, int cap) {
    __shared__ int cnt;
    int t = threadIdx.x;
    if (t == 0) cnt = 0;
    __syncthreads();
    uint_t u = x[t * 37];
    uint_t lo_exp = (u >> 7) & 0xFF;
    atomicAdd(&cnt, (lo_exp >= 96 && lo_exp <= 150) ? 1 : 0);
    __syncthreads();
    int isb = (cnt > 192) ? 1 : 0;
    if (blockIdx.x == 0) {
        if (t == 0) {
            dflag[0] = isb;
            float c1 = 0.f;
            for (int o = 0; o < 15; ++o) c1 += loadf(We1, o, isb) * loadf(e1v, o, isb);
            float c2 = 0.f;
            for (int o = 0; o < 10; ++o) c2 += loadf(We2, o, isb) * loadf(e2v, o, isb);
            cbuf[0] = c1;
            cbuf[1] = c2;
        }
        for (int i = t; i < NBUCK; i += 256) bcur[i] = i * cap;
        stats1[t] = 0.f;
        stats2[t] = 0.f;
        for (int idx = t; idx < 15 * 40; idx += 256) {
            int f = idx / 40, j = idx % 40, r = j / 10, o = j % 10;
            Wf2[idx] = loadf(W2, (r * 15 + f) * 10 + o, isb);
        }
    }
    // grid-stride over the 20*64*8 = 10240 Wsw elements
    for (int idx = blockIdx.x * 256 + t; idx < 20 * 64 * 8; idx += gridDim.x * 256) {
        int j = idx & 7, lane = (idx >> 3) & 63, fr = idx >> 9;
        int ks = fr / 5, ct = fr % 5;
        int k = ks * 32 + (lane >> 4) * 8 + j;   // feature row in [0,128)
        int c = ct * 16 + (lane & 15);           // packed col in [0,80)
        float v = 0.f;
        if (c < 64) {
            int r = c >> 4, o = c & 15;
            if (o < 15) {
                v = loadf(W1, (r * 128 + k) * 15 + o, isb);
            } else {   // col 15 of each relation block: k-projection (dk)
                float s = 0.f;
#pragma unroll
                for (int oo = 0; oo < 15; ++oo)
                    s += loadf(W1, (r * 128 + k) * 15 + oo, isb) * loadf(k1b, oo, isb);
                v = s;
            }
        } else if (c < 68) {   // q-projection (dq) for relation c-64
            int r = c - 64;
            float s = 0.f;
#pragma unroll
            for (int oo = 0; oo < 15; ++oo)
                s += loadf(W1, (r * 128 + k) * 15 + oo, isb) * loadf(q1b, oo, isb);
            v = s;
        }
        Wsw[idx] = f2bf(v);
    }
}

// ---------------- LDS-staged bucket partition (fixed-capacity buckets) ----------------
// tmp record: x = src | et<<23 | ldst<<25 ; y = bkt<<16 | bf16(eattr)
__global__ __launch_bounds__(512) void k_bucket(const int* __restrict__ ei,
                                                const int* __restrict__ et,
                                                const void* __restrict__ ea,
                                                const int* __restrict__ flag,
                                                int* __restrict__ bcur,
                                                int2* __restrict__ tmp,
                                                int E, int npb) {
    extern __shared__ int2 srec[];           // REC records = 32 KB
    __shared__ int cnt[NBUCK];
    __shared__ int lofs[NBUCK + 1];
    __shared__ int gpos[NBUCK];
    int t = threadIdx.x;
    int isb = flag[0];
    cnt[t] = 0;
    __syncthreads();
    int e0 = blockIdx.x * REC;
    for (int i = 0; i < REC / 512; ++i) {
        int e = e0 + i * 512 + t;
        if (e < E) atomicAdd(&cnt[ei[E + e] / npb], 1);
    }
    __syncthreads();
    int myc = cnt[t];
    for (int off = 1; off < NBUCK; off <<= 1) {
        int v = (t >= off) ? cnt[t - off] : 0;
        __syncthreads();
        cnt[t] += v;
        __syncthreads();
    }
    lofs[t] = cnt[t] - myc;
    if (t == NBUCK - 1) lofs[NBUCK] = cnt[NBUCK - 1];
    __syncthreads();
    cnt[t] = lofs[t];   // reuse as local cursor
    __syncthreads();
    for (int i = 0; i < REC / 512; ++i) {
        int e = e0 + i * 512 + t;
        if (e < E) {
            int d = ei[E + e];
            int b = d / npb;
            int ldst = d - b * npb;
            int idx = atomicAdd(&cnt[b], 1);
            int2 r;
            r.x = (int)((uint_t)ei[e] | ((uint_t)et[e] << 23) | ((uint_t)ldst << 25));
            r.y = (int)(((uint_t)b << 16) | (uint_t)f2bf(loadf(ea, e, isb)));
            srec[idx] = r;
        }
    }
    __syncthreads();
    int c_b = lofs[t + 1] - lofs[t];
    gpos[t] = atomicAdd(&bcur[t], c_b);
    __syncthreads();
    int total = lofs[NBUCK];
    for (int i = t; i < total; i += 512) {
        int2 rr = srec[i];
        int bkt = (int)(((uint_t)rr.y) >> 16);   // bucket id from record (no binary search)
        tmp[gpos[bkt] + (i - lofs[bkt])] = rr;
    }
}

// ---------------- per-bucket finalize: node-sorted ebuf + rs/re ----------------
// ebuf record: x = src | et<<20 ; y = dst<<16 | bf16(eattr)
__global__ __launch_bounds__(256) void k_b2csr(const int2* __restrict__ tmp,
                                               const int* __restrict__ bcur,
                                               int* __restrict__ rs,
                                               int* __restrict__ re,
                                               int2* __restrict__ ebuf,
                                               int N, int npb, int cap) {
    __shared__ int cnt[128];
    __shared__ int lofs[129];
    int b = blockIdx.x, t = threadIdx.x;
    int s0 = b * cap;
    int s1 = bcur[b];                 // base + count (post-partition)
    if (t < 128) cnt[t] = 0;
    __syncthreads();
    for (int p = s0 + t; p < s1; p += 256) {
        uint_t x = (uint_t)tmp[p].x;
        atomicAdd(&cnt[(x >> 25) & 0x7F], 1);
    }
    __syncthreads();
    int myc = (t < 128) ? cnt[t] : 0;
    for (int off = 1; off < 128; off <<= 1) {
        int v = (t >= off && t < 128) ? cnt[t - off] : 0;
        __syncthreads();
        if (t < 128) cnt[t] += v;
        __syncthreads();
    }
    if (t < 128) {
        lofs[t] = cnt[t] - myc;
        if (t == 127) lofs[128] = cnt[127];
    }
    __syncthreads();
    int node0 = b * npb;
    if (t < npb && node0 + t < N) {
        rs[node0 + t] = s0 + lofs[t];
        re[node0 + t] = s0 + lofs[t + 1];
    }
    if (t < 128) cnt[t] = lofs[t];   // reuse as cursor
    __syncthreads();
    for (int p = s0 + t; p < s1; p += 256) {
        int2 r = tmp[p];
        uint_t x = (uint_t)r.x;
        int ldst = (x >> 25) & 0x7F;
        int idx = atomicAdd(&cnt[ldst], 1);
        int2 o;
        o.x = (int)(x & 0x7FFFFF) | (((int)(x >> 23) & 3) << 20);  // src | et<<20
        o.y = (int)(((uint_t)(node0 + ldst) << 16) |
                    ((uint_t)r.y & 0xFFFFu));                      // dst | bf16(ea)
        ebuf[s0 + idx] = o;
    }
}

// ---------------- layer-1 transform: MFMA GEMM, bf16 xt out (slot15 = f16 dk) ----------------
__global__ __launch_bounds__(256) void k_t1(const void* __restrict__ xin,
                                            const ushort_t* __restrict__ Wsw,
                                            const int* __restrict__ flag,
                                            ushort_t* __restrict__ xt,
                                            float* __restrict__ dq,
                                            int N, int ntiles, int nwaves) {
    int isb = flag[0];
    int lane = threadIdx.x & 63;
    int gw = blockIdx.x * 4 + (threadIdx.x >> 6);
    bf16x8 bfr[20];
    const uint4* wq = (const uint4*)Wsw;
#pragma unroll
    for (int fr = 0; fr < 20; ++fr)
        bfr[fr] = __builtin_bit_cast(bf16x8, wq[fr * 64 + lane]);
    int row = lane & 15, quad = lane >> 4;
    for (int tile = gw; tile < ntiles; tile += nwaves) {
        int n0 = tile * 16;
        f32x4 acc[5];
#pragma unroll
        for (int ct = 0; ct < 5; ++ct) acc[ct] = (f32x4){0.f, 0.f, 0.f, 0.f};
        int nA = n0 + row;
        if (nA >= N) nA = N - 1;
#pragma unroll
        for (int ks = 0; ks < 4; ++ks) {
            bf16x8 af;
            if (isb) {
                uint4 u = *(const uint4*)((const ushort_t*)xin + (size_t)nA * 128 + ks * 32 + quad * 8);
                af = __builtin_bit_cast(bf16x8, u);
            } else {
                const float* xf = (const float*)xin + (size_t)nA * 128 + ks * 32 + quad * 8;
#pragma unroll
                for (int j = 0; j < 8; ++j) af[j] = (short)f2bf(xf[j]);
            }
#pragma unroll
            for (int ct = 0; ct < 5; ++ct)
                acc[ct] = __builtin_amdgcn_mfma_f32_16x16x32_bf16(af, bfr[ks * 5 + ct], acc[ct], 0, 0, 0);
        }
#pragma unroll
        for (int i = 0; i < 4; ++i) {
            int n = n0 + quad * 4 + i;
            if (n < N) {
#pragma unroll
                for (int ct = 0; ct < 4; ++ct) {
                    float val = acc[ct][i];
                    // row 15 holds dk (k-projection packed as GEMM col 15) -> f16
                    ushort_t bits = (row == 15) ? f2h(val) : f2bf(val);
                    xt[(size_t)n * 64 + ct * 16 + row] = bits;
                }
                if (row < 4) dq[n * 4 + row] = acc[4][i];
            }
        }
    }
}

// ---------------- layer-2 transform: BN1+ELU fused, wave-per-relation, bf16 xt ----------------
__global__ __launch_bounds__(256) void k_t2(const float* __restrict__ in,
                                            const float* __restrict__ stats,
                                            const void* __restrict__ g,
                                            const void* __restrict__ beta,
                                            const float* __restrict__ Wf,
                                            const void* __restrict__ qb,
                                            const void* __restrict__ kb,
                                            const int* __restrict__ flag,
                                            ushort_t* __restrict__ xt,
                                            float* __restrict__ dq, int N) {
    int isb = flag[0];
    int t = threadIdx.x;
    int lane = t & 63;
    int r = t >> 6;                 // wave-uniform relation
    int n = blockIdx.x * 64 + lane;
    if (n >= N) return;
    float invN = 1.f / (float)N;
    float v[15];
#pragma unroll
    for (int c = 0; c < 15; ++c) {
        float mean = stats[c * 16] * invN;
        float var = stats[c * 16 + 8] * invN - mean * mean;
        float inv = rsqrtf(var + BN_EPS);
        float h = (in[(size_t)n * 15 + c] - mean) * inv * loadf(g, c, isb) + loadf(beta, c, isb);
        v[c] = h > 0.f ? h : expm1f(h);  // ELU
    }
    float acc[10];
#pragma unroll
    for (int o = 0; o < 10; ++o) acc[o] = 0.f;
#pragma unroll
    for (int f = 0; f < 15; ++f) {
        const float* wp = Wf + f * 40 + r * 10;
#pragma unroll
        for (int o = 0; o < 10; ++o) acc[o] += v[f] * wp[o];
    }
    float sq = 0.f, sk = 0.f;
#pragma unroll
    for (int o = 0; o < 10; ++o) {
        sq += acc[o] * loadf(qb, o, isb);
        sk += acc[o] * loadf(kb, o, isb);
    }
    dq[n * 4 + r] = sq;
    ushort_t* xr = xt + (size_t)n * 64 + r * 16;
    uint_t pk[8];
#pragma unroll
    for (int j = 0; j < 5; ++j)
        pk[j] = (uint_t)f2bf(acc[2 * j]) | ((uint_t)f2bf(acc[2 * j + 1]) << 16);
    pk[5] = 0; pk[6] = 0;
    pk[7] = ((uint_t)f2h(sk)) << 16;   // slot 15 = dk (f16), slot 14 = 0
    *(uint4*)(xr)     = make_uint4(pk[0], pk[1], pk[2], pk[3]);
    *(uint4*)(xr + 8) = make_uint4(pk[4], pk[5], pk[6], pk[7]);
}

// ---------------- per-node gather with FUSED alpha: single pass, 4-way unrolled ----------------
// 4 edge-groups x 16 channel-lanes. Per edge: 32B xt line already carries dk
// in slot 15 (lane ch==15); dq[n*4+et] is wave-uniform (4 regs, cndmask
// select); alpha = dq + dk + c*ea, e = exp(leakyrelu(alpha)) computed by all
// 16 lanes of the group (1 wave-slot/edge). s accumulated in every lane and
// reduced with the same xor(16)+xor(32) pattern as acc (round-12 lesson).
template <int O>
__global__ __launch_bounds__(256) void k_gather(const int* __restrict__ rs,
                                                const int* __restrict__ re,
                                                const int2* __restrict__ ebuf,
                                                const ushort_t* __restrict__ xt,
                                                const float* __restrict__ dq,
                                                const float* __restrict__ cp,
                                                const void* __restrict__ bb,
                                                const int* __restrict__ flag,
                                                float* __restrict__ out, int N) {
    int isb = flag[0];
    int lane = threadIdx.x & 63;
    int w = threadIdx.x >> 6;
    int n = blockIdx.x * 4 + w;
    if (n >= N) return;
    int start = rs[n], end = re[n];
    int ch = lane & 15;
    int gb = lane & 48;               // group base lane (g*16)
    bool hi15 = (ch == 15);
    float c = cp[0];
    float q0 = dq[n * 4], q1 = dq[n * 4 + 1], q2 = dq[n * 4 + 2], q3 = dq[n * 4 + 3];
    float acc = 0.f, s = 0.f;
    int p = start + (gb >> 4);
    // 4-way unrolled body: advances 16 edges (4 per group) per step
    for (; p + 12 < end; p += 16) {
        int2 v0 = ebuf[p];
        int2 v1 = ebuf[p + 4];
        int2 v2 = ebuf[p + 8];
        int2 v3 = ebuf[p + 12];
        ushort_t u0 = xt[(size_t)((v0.x & 0xFFFFF) * 4 + (v0.x >> 20)) * 16 + ch];
        ushort_t u1 = xt[(size_t)((v1.x & 0xFFFFF) * 4 + (v1.x >> 20)) * 16 + ch];
        ushort_t u2 = xt[(size_t)((v2.x & 0xFFFFF) * 4 + (v2.x >> 20)) * 16 + ch];
        ushort_t u3 = xt[(size_t)((v3.x & 0xFFFFF) * 4 + (v3.x >> 20)) * 16 + ch];
        float x0 = hi15 ? h2f(u0) : bf2f(u0);
        float x1 = hi15 ? h2f(u1) : bf2f(u1);
        float x2 = hi15 ? h2f(u2) : bf2f(u2);
        float x3 = hi15 ? h2f(u3) : bf2f(u3);
        float dk0 = __shfl(x0, gb + 15, 64);
        float dk1 = __shfl(x1, gb + 15, 64);
        float dk2 = __shfl(x2, gb + 15, 64);
        float dk3 = __shfl(x3, gb + 15, 64);
        float a0 = sel4(q0, q1, q2, q3, v0.x >> 20) + dk0 + c * bf2f((ushort_t)(v0.y & 0xFFFFu));
        float a1 = sel4(q0, q1, q2, q3, v1.x >> 20) + dk1 + c * bf2f((ushort_t)(v1.y & 0xFFFFu));
        float a2 = sel4(q0, q1, q2, q3, v2.x >> 20) + dk2 + c * bf2f((ushort_t)(v2.y & 0xFFFFu));
        float a3 = sel4(q0, q1, q2, q3, v3.x >> 20) + dk3 + c * bf2f((ushort_t)(v3.y & 0xFFFFu));
        float e0 = __expf(fmaxf(a0, NEG_SLOPE * a0));
        float e1 = __expf(fmaxf(a1, NEG_SLOPE * a1));
        float e2 = __expf(fmaxf(a2, NEG_SLOPE * a2));
        float e3 = __expf(fmaxf(a3, NEG_SLOPE * a3));
        s += (e0 + e1) + (e2 + e3);
        acc += e0 * x0;
        acc += e1 * x1;
        acc += e2 * x2;
        acc += e3 * x3;
    }
    for (; p < end; p += 4) {
        int2 v = ebuf[p];
        ushort_t u = xt[(size_t)((v.x & 0xFFFFF) * 4 + (v.x >> 20)) * 16 + ch];
        float x = hi15 ? h2f(u) : bf2f(u);
        float dk = __shfl(x, gb + 15, 64);
        float a = sel4(q0, q1, q2, q3, v.x >> 20) + dk + c * bf2f((ushort_t)(v.y & 0xFFFFu));
        float e = __expf(fmaxf(a, NEG_SLOPE * a));
        acc += e * x;
        s += e;
    }
    s   += __shfl_xor(s, 16, 64);
    s   += __shfl_xor(s, 32, 64);
    acc += __shfl_xor(acc, 16, 64);
    acc += __shfl_xor(acc, 32, 64);
    if (lane < O) out[(size_t)n * O + lane] = acc / (s + 1e-16f) + loadf(bb, lane, isb);
}

// ---------------- BN batch statistics (separate, low-block-count) ----------------
// stats layout: channel c -> S[c*16] = sum, S[c*16+8] = sumsq (64B stride)
template <int C>
__global__ __launch_bounds__(256) void k_bnstats(const float* __restrict__ in,
                                                 float* __restrict__ S, int N) {
    int t = threadIdx.x;
    int ch = t & 15, rg = t >> 4;
    float s1 = 0.f, s2 = 0.f;
    int row0 = blockIdx.x * 256;
    int rowEnd = row0 + 256;
    if (rowEnd > N) rowEnd = N;
    if (ch < C) {
        for (int r = row0 + rg; r < rowEnd; r += 16) {
            float v = in[(size_t)r * C + ch];
            s1 += v;
            s2 += v * v;
        }
    }
    __shared__ float L1[256], L2[256];
    L1[t] = s1; L2[t] = s2;
    __syncthreads();
    for (int k = 128; k >= 16; k >>= 1) {
        if (t < k) { L1[t] += L1[t + k]; L2[t] += L2[t + k]; }
        __syncthreads();
    }
    if (t < C) {
        atomicAdd(&S[t * 16], L1[t]);
        atomicAdd(&S[t * 16 + 8], L2[t]);
    }
}

// ---------------- BN2 + ELU + head, bf16-or-fp32 output ----------------
__global__ __launch_bounds__(256) void k_head(const float* __restrict__ in,
                                              const float* __restrict__ stats,
                                              const void* __restrict__ g,
                                              const void* __restrict__ beta,
                                              const void* __restrict__ wh,
                                              const void* __restrict__ bh,
                                              const int* __restrict__ flag,
                                              void* __restrict__ out, int N) {
    int isb = flag[0];
    int n = blockIdx.x * 256 + threadIdx.x;
    if (n >= N) return;
    float invN = 1.f / (float)N;
    float r = loadf(bh, 0, isb);
#pragma unroll
    for (int c = 0; c < 10; ++c) {
        float mean = stats[c * 16] * invN;
        float var = stats[c * 16 + 8] * invN - mean * mean;
        float inv = rsqrtf(var + BN_EPS);
        float h = (in[(size_t)n * 10 + c] - mean) * inv * loadf(g, c, isb) + loadf(beta, c, isb);
        float e = h > 0.f ? h : expm1f(h);
        r += e * loadf(wh, c, isb);
    }
    if (isb) ((ushort_t*)out)[n] = f2bf(r);
    else     ((float*)out)[n] = r;
}

extern "C" void kernel_launch(void* const* d_in, const int* in_sizes, int n_in,
                              void* d_out, int out_size, void* d_ws, size_t ws_size,
                              hipStream_t stream) {
    const void* node_emb  = d_in[0];
    const int*  edge_index = (const int*)d_in[1];
    const int*  edge_types = (const int*)d_in[2];
    const void* edge_attr = d_in[3];
    const void* W1  = d_in[4];
    const void* q1  = d_in[5];
    const void* k1  = d_in[6];
    const void* e1  = d_in[7];
    const void* We1 = d_in[8];
    const void* b1  = d_in[9];
    const void* W2  = d_in[10];
    const void* q2  = d_in[11];
    const void* k2  = d_in[12];
    const void* e2  = d_in[13];
    const void* We2 = d_in[14];
    const void* b2  = d_in[15];
    const void* g1  = d_in[16];
    const void* beta1 = d_in[17];
    const void* g2  = d_in[18];
    const void* beta2 = d_in[19];
    const void* w_head = d_in[20];
    const void* b_head = d_in[21];

    int N = in_sizes[0] / 128;
    int E = in_sizes[1] / 2;
    int npb = (N + NBUCK - 1) / NBUCK;         // nodes per bucket (98)
    int nbuck = (N + npb - 1) / npb;           // used buckets (511)
    int cap = E / nbuck + 512;                 // ~9 sigma slack for random dst
    size_t slots = (size_t)nbuck * cap;        // padded edge-slot count

    char* ws = (char*)d_ws;
    size_t off = 0;
    auto alloc = [&](size_t bytes) -> void* {
        void* p = ws + off;
        off = (off + bytes + 255) & ~(size_t)255;
        return p;
    };
    int*   rs      = (int*)alloc((size_t)N * 4);
    int*   re      = (int*)alloc((size_t)N * 4);
    int*   bcur    = (int*)alloc((NBUCK) * 4);
    int*   dflag   = (int*)alloc(256);
    float* cbuf    = (float*)alloc(256);
    int2*  ebuf    = (int2*)alloc(slots * 8);
    // xt (bf16, 32B per (node,rel) row) overlays etmp: tmp dead before k_t1
    size_t big = (size_t)N * 64 * 2;
    if (slots * 8 > big) big = slots * 8;
    ushort_t* xt1  = (ushort_t*)alloc(big);
    int2*  etmp    = (int2*)xt1;
    float* dq1     = (float*)alloc((size_t)N * 16);
    float* out1    = (float*)alloc((size_t)N * 15 * 4);   // out2 overlays
    float* stats1  = (float*)alloc(256 * 4);   // 16 floats (64B) per channel
    float* stats2  = (float*)alloc(256 * 4);
    ushort_t* Wsw  = (ushort_t*)alloc(20 * 64 * 8 * 2);   // 20 KB B-frags
    float* Wf2     = (float*)alloc(600 * 4);
    // overlays (lifetimes disjoint):
    ushort_t* xt2 = xt1;
    float* dq2  = dq1;
    float* out2 = out1;

    int NB_N = (N + 255) / 256;
    int NB_T2 = (N + 63) / 64;
    int NB_G = (N + 3) / 4;
    int NB_B = (E + REC - 1) / REC;      // 391 blocks, 32 KB LDS, 4 blocks/CU
    int ntiles = (N + 15) / 16;
    int NB_T1 = 391;
    int nwaves = NB_T1 * 4;

    k_prep<<<40, 256, 0, stream>>>((const uint_t*)node_emb, W1, W2, q1, k1,
                                   We1, e1, We2, e2,
                                   dflag, bcur, stats1, stats2, cbuf, Wsw, Wf2, cap);
    k_bucket<<<NB_B, 512, REC * sizeof(int2), stream>>>(edge_index, edge_types, edge_attr,
                                                        dflag, bcur, etmp, E, npb);
    k_b2csr<<<nbuck, 256, 0, stream>>>(etmp, bcur, rs, re, ebuf, N, npb, cap);

    k_t1<<<NB_T1, 256, 0, stream>>>(node_emb, Wsw, dflag, xt1, dq1, N, ntiles, nwaves);
    k_gather<15><<<NB_G, 256, 0, stream>>>(rs, re, ebuf, xt1, dq1, cbuf, b1, dflag, out1, N);
    k_bnstats<15><<<NB_N, 256, 0, stream>>>(out1, stats1, N);
    k_t2<<<NB_T2, 256, 0, stream>>>(out1, stats1, g1, beta1, Wf2, q2, k2, dflag, xt2, dq2, N);
    k_gather<10><<<NB_G, 256, 0, stream>>>(rs, re, ebuf, xt2, dq2, cbuf + 1, b2, dflag, out2, N);
    k_bnstats<10><<<NB_N, 256, 0, stream>>>(out2, stats2, N);
    k_head<<<NB_N, 256, 0, stream>>>(out2, stats2, g2, beta2, w_head, b_head, dflag, d_out, N);
}